// Round 2
// baseline (545.761 us; speedup 1.0000x reference)
//
#include <hip/hip_runtime.h>
#include <cstdint>

typedef short bf16x8 __attribute__((ext_vector_type(8)));
typedef float f32x4 __attribute__((ext_vector_type(4)));

#define NEG_MAX 3.402823466e38f

__device__ __forceinline__ unsigned short f2bf(float f) {
  uint32_t u = __builtin_bit_cast(uint32_t, f);
  u += 0x7FFFu + ((u >> 16) & 1u);
  return (unsigned short)(u >> 16);
}

__global__ __launch_bounds__(256) void cvt_f32_bf16(const float* __restrict__ in,
                                                    unsigned short* __restrict__ out, int n4) {
  int i = blockIdx.x * 256 + threadIdx.x;
  if (i >= n4) return;
  float4 v = reinterpret_cast<const float4*>(in)[i];
  ushort4 o;
  o.x = f2bf(v.x); o.y = f2bf(v.y); o.z = f2bf(v.z); o.w = f2bf(v.w);
  reinterpret_cast<ushort4*>(out)[i] = o;
}

// C = A @ Bw^T + bias;  A:[4096][1024] bf16 row-major, Bw:[1024][1024] bf16 row-major.
// MODE 0: write bf16 head-split [B,H,S,64]; MODE 1: bf16 [B,H,64,S]; MODE 2: fp32 [4096][1024].
template <int MODE>
__global__ __launch_bounds__(256) void gemm_bt(const unsigned short* __restrict__ A,
                                               const unsigned short* __restrict__ Bw,
                                               const float* __restrict__ bias,
                                               float* __restrict__ Cf,
                                               unsigned short* __restrict__ Cb) {
  constexpr int KD = 1024;
  __shared__ __align__(16) unsigned short Al[128 * 32];
  __shared__ __align__(16) unsigned short Bl[128 * 32];
  const int tid = threadIdx.x;
  const int l = tid & 63;
  const int w = tid >> 6;
  const int lr = l & 15;
  const int lg = l >> 4;
  const int gm = blockIdx.y;
  const int gn = blockIdx.x;
  const int wr = w >> 1;
  const int wc = w & 1;

  f32x4 acc[4][4];
#pragma unroll
  for (int m = 0; m < 4; ++m)
#pragma unroll
    for (int n = 0; n < 4; ++n) acc[m][n] = (f32x4){0.f, 0.f, 0.f, 0.f};

  const int c0 = w * 2;              // this wave's first 1KB chunk (of 8)
  const int srow = (l >> 2);         // 0..15 row within chunk
  const int scol = (l & 3) * 8;      // bf16 col within 32

  const unsigned short* gA = A + (size_t)(gm * 128) * KD;
  const unsigned short* gB = Bw + (size_t)(gn * 128) * KD;

  for (int kt = 0; kt < 32; ++kt) {
    const int k0 = kt * 32;
    const unsigned short* a0 = gA + (size_t)(c0 * 16 + srow) * KD + k0 + scol;
    const unsigned short* a1 = a0 + (size_t)16 * KD;
    const unsigned short* b0 = gB + (size_t)(c0 * 16 + srow) * KD + k0 + scol;
    const unsigned short* b1 = b0 + (size_t)16 * KD;
    __builtin_amdgcn_global_load_lds((const __attribute__((address_space(1))) void*)a0,
                                     (__attribute__((address_space(3))) void*)&Al[c0 * 512], 16, 0, 0);
    __builtin_amdgcn_global_load_lds((const __attribute__((address_space(1))) void*)a1,
                                     (__attribute__((address_space(3))) void*)&Al[c0 * 512 + 512], 16, 0, 0);
    __builtin_amdgcn_global_load_lds((const __attribute__((address_space(1))) void*)b0,
                                     (__attribute__((address_space(3))) void*)&Bl[c0 * 512], 16, 0, 0);
    __builtin_amdgcn_global_load_lds((const __attribute__((address_space(1))) void*)b1,
                                     (__attribute__((address_space(3))) void*)&Bl[c0 * 512 + 512], 16, 0, 0);
    __syncthreads();
    bf16x8 af[4], bfr[4];
#pragma unroll
    for (int m = 0; m < 4; ++m)
      af[m] = *reinterpret_cast<const bf16x8*>(&Al[(wr * 64 + m * 16 + lr) * 32 + lg * 8]);
#pragma unroll
    for (int n = 0; n < 4; ++n)
      bfr[n] = *reinterpret_cast<const bf16x8*>(&Bl[(wc * 64 + n * 16 + lr) * 32 + lg * 8]);
#pragma unroll
    for (int m = 0; m < 4; ++m)
#pragma unroll
      for (int n = 0; n < 4; ++n)
        acc[m][n] = __builtin_amdgcn_mfma_f32_16x16x32_bf16(af[m], bfr[n], acc[m][n], 0, 0, 0);
    __syncthreads();
  }

#pragma unroll
  for (int m = 0; m < 4; ++m) {
#pragma unroll
    for (int n = 0; n < 4; ++n) {
      const int colg = gn * 128 + wc * 64 + n * 16 + lr;
      const float bv = bias[colg];
#pragma unroll
      for (int r = 0; r < 4; ++r) {
        const int rowg = gm * 128 + wr * 64 + m * 16 + lg * 4 + r;
        const float v = acc[m][n][r] + bv;
        if (MODE == 2) {
          Cf[(size_t)rowg * 1024 + colg] = v;
        } else {
          const int bb = rowg >> 11, ss = rowg & 2047;
          const int hh = colg >> 6, dk = colg & 63;
          if (MODE == 0)
            Cb[(((size_t)bb * 16 + hh) * 2048 + ss) * 64 + dk] = f2bf(v);
          else
            Cb[(((size_t)bb * 16 + hh) * 64 + dk) * 2048 + ss] = f2bf(v);
        }
      }
    }
  }
}

// One block = (b,h, 64 q-rows). 4 waves, each owns 16 q-rows.
// Phase 1: online max/sum over all K. Phase 2: recompute logits, write fp32 weights,
// accumulate PV via LDS round-trip of bf16 W.
__global__ __launch_bounds__(256) void attn_fused(const unsigned short* __restrict__ Q,
                                                  const unsigned short* __restrict__ Kb,
                                                  const unsigned short* __restrict__ Vt,
                                                  const float* __restrict__ mask,
                                                  float* __restrict__ wout,
                                                  unsigned short* __restrict__ ctx) {
  const int tid = threadIdx.x;
  const int l = tid & 63;
  const int w = tid >> 6;
  const int qt = blockIdx.x & 31;
  const int bh = blockIdx.x >> 5;
  const int b = bh >> 4;
  const int h = bh & 15;
  const int q0 = qt * 64;
  const int lr = l & 15;
  const int lg = l >> 4;

  __shared__ __align__(16) unsigned short Kl[64 * 72];
  __shared__ __align__(16) unsigned short Vl[64 * 72];
  __shared__ __align__(16) unsigned short Wl[64 * 72];

  // Q fragments for this wave's 16 rows (persist whole kernel)
  const size_t qoff = ((size_t)bh * 2048 + (q0 + w * 16 + lr)) * 64 + lg * 8;
  const bf16x8 qf0 = *reinterpret_cast<const bf16x8*>(Q + qoff);
  const bf16x8 qf1 = *reinterpret_cast<const bf16x8*>(Q + qoff + 32);

  const int r0 = tid >> 3;            // staging row 0..31
  const int c0s = (tid & 7) * 8;      // staging col (bf16)
  const float* mbase = mask + (size_t)b * 2048 * 2048;

  float mrow[4], srow[4];
#pragma unroll
  for (int r = 0; r < 4; ++r) { mrow[r] = -NEG_MAX; srow[r] = 0.f; }

  // ---------------- Phase 1 ----------------
  for (int kt = 0; kt < 32; ++kt) {
    const int kg = kt * 64;
    {
      bf16x8 k0v = *reinterpret_cast<const bf16x8*>(Kb + ((size_t)bh * 2048 + kg + r0) * 64 + c0s);
      bf16x8 k1v = *reinterpret_cast<const bf16x8*>(Kb + ((size_t)bh * 2048 + kg + r0 + 32) * 64 + c0s);
      *reinterpret_cast<bf16x8*>(&Kl[r0 * 72 + c0s]) = k0v;
      *reinterpret_cast<bf16x8*>(&Kl[(r0 + 32) * 72 + c0s]) = k1v;
    }
    __syncthreads();
    f32x4 acc[4];
#pragma unroll
    for (int n = 0; n < 4; ++n) {
      acc[n] = (f32x4){0.f, 0.f, 0.f, 0.f};
      bf16x8 kb0 = *reinterpret_cast<const bf16x8*>(&Kl[(n * 16 + lr) * 72 + lg * 8]);
      bf16x8 kb1 = *reinterpret_cast<const bf16x8*>(&Kl[(n * 16 + lr) * 72 + 32 + lg * 8]);
      acc[n] = __builtin_amdgcn_mfma_f32_16x16x32_bf16(qf0, kb0, acc[n], 0, 0, 0);
      acc[n] = __builtin_amdgcn_mfma_f32_16x16x32_bf16(qf1, kb1, acc[n], 0, 0, 0);
    }
#pragma unroll
    for (int r = 0; r < 4; ++r) {
      const int qrow = q0 + w * 16 + lg * 4 + r;
      const float* mp = mbase + (size_t)qrow * 2048 + kg;
      float lv[4];
      float tm = -NEG_MAX;
#pragma unroll
      for (int n = 0; n < 4; ++n) {
        const float mv = mp[n * 16 + lr];
        const float x = acc[n][r] * 0.125f + (1.0f - mv) * (-NEG_MAX);
        lv[n] = x;
        tm = fmaxf(tm, x);
      }
#pragma unroll
      for (int d = 1; d < 16; d <<= 1) tm = fmaxf(tm, __shfl_xor(tm, d));
      const float nm = fmaxf(mrow[r], tm);
      float ps = 0.f;
#pragma unroll
      for (int n = 0; n < 4; ++n) ps += __expf(lv[n] - nm);
#pragma unroll
      for (int d = 1; d < 16; d <<= 1) ps += __shfl_xor(ps, d);
      srow[r] = srow[r] * __expf(mrow[r] - nm) + ps;
      mrow[r] = nm;
    }
    __syncthreads();
  }

  float inv_s[4];
#pragma unroll
  for (int r = 0; r < 4; ++r) inv_s[r] = 1.0f / srow[r];

  f32x4 cacc[4];
#pragma unroll
  for (int n = 0; n < 4; ++n) cacc[n] = (f32x4){0.f, 0.f, 0.f, 0.f};

  // ---------------- Phase 2 ----------------
  for (int kt = 0; kt < 32; ++kt) {
    const int kg = kt * 64;
    {
      bf16x8 k0v = *reinterpret_cast<const bf16x8*>(Kb + ((size_t)bh * 2048 + kg + r0) * 64 + c0s);
      bf16x8 k1v = *reinterpret_cast<const bf16x8*>(Kb + ((size_t)bh * 2048 + kg + r0 + 32) * 64 + c0s);
      *reinterpret_cast<bf16x8*>(&Kl[r0 * 72 + c0s]) = k0v;
      *reinterpret_cast<bf16x8*>(&Kl[(r0 + 32) * 72 + c0s]) = k1v;
      bf16x8 v0v = *reinterpret_cast<const bf16x8*>(Vt + ((size_t)bh * 64 + r0) * 2048 + kg + c0s);
      bf16x8 v1v = *reinterpret_cast<const bf16x8*>(Vt + ((size_t)bh * 64 + r0 + 32) * 2048 + kg + c0s);
      *reinterpret_cast<bf16x8*>(&Vl[r0 * 72 + c0s]) = v0v;
      *reinterpret_cast<bf16x8*>(&Vl[(r0 + 32) * 72 + c0s]) = v1v;
    }
    __syncthreads();
    f32x4 acc[4];
#pragma unroll
    for (int n = 0; n < 4; ++n) {
      acc[n] = (f32x4){0.f, 0.f, 0.f, 0.f};
      bf16x8 kb0 = *reinterpret_cast<const bf16x8*>(&Kl[(n * 16 + lr) * 72 + lg * 8]);
      bf16x8 kb1 = *reinterpret_cast<const bf16x8*>(&Kl[(n * 16 + lr) * 72 + 32 + lg * 8]);
      acc[n] = __builtin_amdgcn_mfma_f32_16x16x32_bf16(qf0, kb0, acc[n], 0, 0, 0);
      acc[n] = __builtin_amdgcn_mfma_f32_16x16x32_bf16(qf1, kb1, acc[n], 0, 0, 0);
    }
#pragma unroll
    for (int r = 0; r < 4; ++r) {
      const int qrow = q0 + w * 16 + lg * 4 + r;
      const float* mp = mbase + (size_t)qrow * 2048 + kg;
      float* wp = wout + ((size_t)bh * 2048 + qrow) * 2048 + kg;
#pragma unroll
      for (int n = 0; n < 4; ++n) {
        const float mv = mp[n * 16 + lr];
        const float x = acc[n][r] * 0.125f + (1.0f - mv) * (-NEG_MAX);
        const float wgt = __expf(x - mrow[r]) * inv_s[r];
        wp[n * 16 + lr] = wgt;
        Wl[(w * 16 + lg * 4 + r) * 72 + n * 16 + lr] = f2bf(wgt);
      }
    }
    __syncthreads();
    const bf16x8 a0 = *reinterpret_cast<const bf16x8*>(&Wl[(w * 16 + lr) * 72 + lg * 8]);
    const bf16x8 a1 = *reinterpret_cast<const bf16x8*>(&Wl[(w * 16 + lr) * 72 + 32 + lg * 8]);
#pragma unroll
    for (int n = 0; n < 4; ++n) {
      bf16x8 vb0 = *reinterpret_cast<const bf16x8*>(&Vl[(n * 16 + lr) * 72 + lg * 8]);
      bf16x8 vb1 = *reinterpret_cast<const bf16x8*>(&Vl[(n * 16 + lr) * 72 + 32 + lg * 8]);
      cacc[n] = __builtin_amdgcn_mfma_f32_16x16x32_bf16(a0, vb0, cacc[n], 0, 0, 0);
      cacc[n] = __builtin_amdgcn_mfma_f32_16x16x32_bf16(a1, vb1, cacc[n], 0, 0, 0);
    }
    __syncthreads();
  }

  // ctx epilogue: [B,S,1024] bf16, col = h*64+dk
#pragma unroll
  for (int n = 0; n < 4; ++n) {
#pragma unroll
    for (int r = 0; r < 4; ++r) {
      const int ss = q0 + w * 16 + lg * 4 + r;
      const int col = h * 64 + n * 16 + lr;
      ctx[((size_t)b * 2048 + ss) * 1024 + col] = f2bf(cacc[n][r]);
    }
  }
}

extern "C" void kernel_launch(void* const* d_in, const int* in_sizes, int n_in,
                              void* d_out, int out_size, void* d_ws, size_t ws_size,
                              hipStream_t stream) {
  const float* query = (const float*)d_in[0];
  const float* key   = (const float*)d_in[1];
  const float* value = (const float*)d_in[2];
  const float* mask  = (const float*)d_in[3];
  const float* wq = (const float*)d_in[4];
  const float* bq = (const float*)d_in[5];
  const float* wk = (const float*)d_in[6];
  const float* bk = (const float*)d_in[7];
  const float* wv = (const float*)d_in[8];
  const float* bv = (const float*)d_in[9];
  const float* wo = (const float*)d_in[10];
  const float* bo = (const float*)d_in[11];

  unsigned short* Qbf = (unsigned short*)d_ws;      // [B,H,S,64] bf16   (8 MB)
  unsigned short* Kbf = Qbf + 4194304;              // [B,H,S,64] bf16   (8 MB)
  unsigned short* Vtb = Kbf + 4194304;              // [B,H,64,S] bf16   (8 MB)
  unsigned short* ctx = Vtb + 4194304;              // [B,S,1024] bf16   (8 MB)
  unsigned short* xbf = ctx + 4194304;              // input staging     (8 MB)
  unsigned short* wbf = xbf + 4194304;              // weight staging    (2 MB)

  float* outp = (float*)d_out;            // [B,S,1024] fp32
  float* wout = outp + 4194304;           // [B,H,S,S] fp32

  dim3 gg(8, 32);

  cvt_f32_bf16<<<4096, 256, 0, stream>>>(query, xbf, 1048576);
  cvt_f32_bf16<<<1024, 256, 0, stream>>>(wq, wbf, 262144);
  gemm_bt<0><<<gg, 256, 0, stream>>>(xbf, wbf, bq, nullptr, Qbf);

  cvt_f32_bf16<<<4096, 256, 0, stream>>>(key, xbf, 1048576);
  cvt_f32_bf16<<<1024, 256, 0, stream>>>(wk, wbf, 262144);
  gemm_bt<0><<<gg, 256, 0, stream>>>(xbf, wbf, bk, nullptr, Kbf);

  cvt_f32_bf16<<<4096, 256, 0, stream>>>(value, xbf, 1048576);
  cvt_f32_bf16<<<1024, 256, 0, stream>>>(wv, wbf, 262144);
  gemm_bt<1><<<gg, 256, 0, stream>>>(xbf, wbf, bv, nullptr, Vtb);

  attn_fused<<<1024, 256, 0, stream>>>(Qbf, Kbf, Vtb, mask, wout, ctx);

  cvt_f32_bf16<<<1024, 256, 0, stream>>>(wo, wbf, 262144);
  gemm_bt<2><<<gg, 256, 0, stream>>>(ctx, wbf, bo, outp, nullptr);
}

// Round 4
// 382.016 us; speedup vs baseline: 1.4286x; 1.4286x over previous
//
#include <hip/hip_runtime.h>
#include <cstdint>

typedef short bf16x8 __attribute__((ext_vector_type(8)));
typedef float f32x4 __attribute__((ext_vector_type(4)));

#define NEG_MAX 3.402823466e38f

__device__ __forceinline__ unsigned short f2bf(float f) {
  uint32_t u = __builtin_bit_cast(uint32_t, f);
  u += 0x7FFFu + ((u >> 16) & 1u);
  return (unsigned short)(u >> 16);
}

__global__ __launch_bounds__(256) void cvt_f32_bf16(const float* __restrict__ in,
                                                    unsigned short* __restrict__ out, int n4) {
  int i = blockIdx.x * 256 + threadIdx.x;
  if (i >= n4) return;
  float4 v = reinterpret_cast<const float4*>(in)[i];
  ushort4 o;
  o.x = f2bf(v.x); o.y = f2bf(v.y); o.z = f2bf(v.z); o.w = f2bf(v.w);
  reinterpret_cast<ushort4*>(out)[i] = o;
}

// Per (b, q64-tile, k64-tile): flag = 1 if mask tile is entirely 1.0f, else 0.
__global__ __launch_bounds__(256) void mask_scan(const float* __restrict__ mask,
                                                 int* __restrict__ flags) {
  const int blk = blockIdx.x;
  const int kt = blk & 31, qt = (blk >> 5) & 31, b = blk >> 10;
  const float* base = mask + ((size_t)b * 2048 + qt * 64) * 2048 + kt * 64;
  const int t = threadIdx.x;
  const int row = t >> 2, c0 = (t & 3) * 16;
  const float4* p = reinterpret_cast<const float4*>(base + (size_t)row * 2048 + c0);
  bool ones = true;
#pragma unroll
  for (int i = 0; i < 4; ++i) {
    float4 v = p[i];
    ones = ones && (v.x == 1.f) && (v.y == 1.f) && (v.z == 1.f) && (v.w == 1.f);
  }
  unsigned long long ball = __ballot(ones);
  __shared__ int sf[4];
  if ((t & 63) == 0) sf[t >> 6] = (ball == ~0ull) ? 1 : 0;
  __syncthreads();
  if (t == 0) flags[blk] = sf[0] & sf[1] & sf[2] & sf[3];
}

// C = A @ Bw^T + bias;  A:[4096][1024] bf16 row-major, Bw:[1024][1024] bf16 row-major.
// MODE 0: write bf16 head-split [B,H,S,64]; MODE 1: bf16 [B,H,64,S]; MODE 2: fp32 [4096][1024].
template <int MODE>
__global__ __launch_bounds__(256) void gemm_bt(const unsigned short* __restrict__ A,
                                               const unsigned short* __restrict__ Bw,
                                               const float* __restrict__ bias,
                                               float* __restrict__ Cf,
                                               unsigned short* __restrict__ Cb) {
  constexpr int KD = 1024;
  __shared__ __align__(16) unsigned short Al[128 * 32];
  __shared__ __align__(16) unsigned short Bl[128 * 32];
  const int tid = threadIdx.x;
  const int l = tid & 63;
  const int w = tid >> 6;
  const int lr = l & 15;
  const int lg = l >> 4;
  const int gm = blockIdx.y;
  const int gn = blockIdx.x;
  const int wr = w >> 1;
  const int wc = w & 1;

  f32x4 acc[4][4];
#pragma unroll
  for (int m = 0; m < 4; ++m)
#pragma unroll
    for (int n = 0; n < 4; ++n) acc[m][n] = (f32x4){0.f, 0.f, 0.f, 0.f};

  const int c0 = w * 2;
  const int srow = (l >> 2);
  const int scol = (l & 3) * 8;

  const unsigned short* gA = A + (size_t)(gm * 128) * KD;
  const unsigned short* gB = Bw + (size_t)(gn * 128) * KD;

  for (int kt = 0; kt < 32; ++kt) {
    const int k0 = kt * 32;
    const unsigned short* a0 = gA + (size_t)(c0 * 16 + srow) * KD + k0 + scol;
    const unsigned short* a1 = a0 + (size_t)16 * KD;
    const unsigned short* b0 = gB + (size_t)(c0 * 16 + srow) * KD + k0 + scol;
    const unsigned short* b1 = b0 + (size_t)16 * KD;
    __builtin_amdgcn_global_load_lds((const __attribute__((address_space(1))) void*)a0,
                                     (__attribute__((address_space(3))) void*)&Al[c0 * 512], 16, 0, 0);
    __builtin_amdgcn_global_load_lds((const __attribute__((address_space(1))) void*)a1,
                                     (__attribute__((address_space(3))) void*)&Al[c0 * 512 + 512], 16, 0, 0);
    __builtin_amdgcn_global_load_lds((const __attribute__((address_space(1))) void*)b0,
                                     (__attribute__((address_space(3))) void*)&Bl[c0 * 512], 16, 0, 0);
    __builtin_amdgcn_global_load_lds((const __attribute__((address_space(1))) void*)b1,
                                     (__attribute__((address_space(3))) void*)&Bl[c0 * 512 + 512], 16, 0, 0);
    __syncthreads();
    bf16x8 af[4], bfr[4];
#pragma unroll
    for (int m = 0; m < 4; ++m)
      af[m] = *reinterpret_cast<const bf16x8*>(&Al[(wr * 64 + m * 16 + lr) * 32 + lg * 8]);
#pragma unroll
    for (int n = 0; n < 4; ++n)
      bfr[n] = *reinterpret_cast<const bf16x8*>(&Bl[(wc * 64 + n * 16 + lr) * 32 + lg * 8]);
#pragma unroll
    for (int m = 0; m < 4; ++m)
#pragma unroll
      for (int n = 0; n < 4; ++n)
        acc[m][n] = __builtin_amdgcn_mfma_f32_16x16x32_bf16(af[m], bfr[n], acc[m][n], 0, 0, 0);
    __syncthreads();
  }

#pragma unroll
  for (int m = 0; m < 4; ++m) {
#pragma unroll
    for (int n = 0; n < 4; ++n) {
      const int colg = gn * 128 + wc * 64 + n * 16 + lr;
      const float bv = bias[colg];
#pragma unroll
      for (int r = 0; r < 4; ++r) {
        const int rowg = gm * 128 + wr * 64 + m * 16 + lg * 4 + r;
        const float v = acc[m][n][r] + bv;
        if (MODE == 2) {
          Cf[(size_t)rowg * 1024 + colg] = v;
        } else {
          const int bb = rowg >> 11, ss = rowg & 2047;
          const int hh = colg >> 6, dk = colg & 63;
          if (MODE == 0)
            Cb[(((size_t)bb * 16 + hh) * 2048 + ss) * 64 + dk] = f2bf(v);
          else
            Cb[(((size_t)bb * 16 + hh) * 64 + dk) * 2048 + ss] = f2bf(v);
        }
      }
    }
  }
}

// One block = (b,h, 64 q-rows), 4 waves x 16 rows. XCD-swizzled blockIdx.
// LDS: K/V double-buffered 64x64 bf16 tiles, 16B-seg XOR swizzle (seg ^= row&7),
// staged via global_load_lds with inverse-swizzled global source.
__global__ __launch_bounds__(256) void attn_fused(const unsigned short* __restrict__ Q,
                                                  const unsigned short* __restrict__ Kb,
                                                  const unsigned short* __restrict__ Vt,
                                                  const float* __restrict__ mask,
                                                  const int* __restrict__ flags,
                                                  float* __restrict__ wout,
                                                  unsigned short* __restrict__ ctx) {
  const int tid = threadIdx.x;
  const int l = tid & 63;
  const int w = tid >> 6;
  const int lr = l & 15;
  const int lg = l >> 4;

  // XCD swizzle: all 32 q-tiles of one (b,h) on one XCD.
  const int d = blockIdx.x;
  const int bh = (d >> 8) * 8 + (d & 7);
  const int qt = (d >> 3) & 31;
  const int b = bh >> 4, h = bh & 15;
  const int q0 = qt * 64;

  __shared__ __align__(16) unsigned short Kl[2][4096];
  __shared__ __align__(16) unsigned short Vl[2][4096];
  __shared__ __align__(16) unsigned short Wl[4096];

  const size_t qoff = ((size_t)bh * 2048 + (q0 + w * 16 + lr)) * 64 + lg * 8;
  const bf16x8 qf0 = *reinterpret_cast<const bf16x8*>(Q + qoff);
  const bf16x8 qf1 = *reinterpret_cast<const bf16x8*>(Q + qoff + 32);

  // staging geometry: 512 16B-segs per tile, wave w covers segs [w*128, w*128+128)
  const int seg0 = w * 128 + l;
  const int seg1 = seg0 + 64;
  const int r0s = seg0 >> 3, c0x = (seg0 & 7) ^ (r0s & 7);
  const int r1s = seg1 >> 3, c1x = (seg1 & 7) ^ (r1s & 7);
  const unsigned short* kB = Kb + (size_t)bh * 131072;
  const unsigned short* vB = Vt + (size_t)bh * 131072;
  const size_t kS0 = (size_t)r0s * 64 + c0x * 8;
  const size_t kS1 = (size_t)r1s * 64 + c1x * 8;
  const size_t vS0 = (size_t)r0s * 2048 + c0x * 8;
  const size_t vS1 = (size_t)r1s * 2048 + c1x * 8;
  const int ldsOff0 = w * 1024;
  const int ldsOff1 = w * 1024 + 512;

  // fragment-read seg offsets (shorts)
  const int sA = (lg ^ (lr & 7)) << 3;
  const int sBo = ((4 + lg) ^ (lr & 7)) << 3;

  const int fbase = (b * 32 + qt) * 32;
  const float* mbase = mask + (size_t)b * 2048 * 2048;

#define STAGE_K(kt_, buf_)                                                                          \
  do {                                                                                              \
    __builtin_amdgcn_global_load_lds(                                                               \
        (const __attribute__((address_space(1))) void*)(kB + (size_t)(kt_) * 4096 + kS0),           \
        (__attribute__((address_space(3))) void*)&Kl[buf_][ldsOff0], 16, 0, 0);                     \
    __builtin_amdgcn_global_load_lds(                                                               \
        (const __attribute__((address_space(1))) void*)(kB + (size_t)(kt_) * 4096 + kS1),           \
        (__attribute__((address_space(3))) void*)&Kl[buf_][ldsOff1], 16, 0, 0);                     \
  } while (0)
#define STAGE_V(kt_, buf_)                                                                          \
  do {                                                                                              \
    __builtin_amdgcn_global_load_lds(                                                               \
        (const __attribute__((address_space(1))) void*)(vB + (size_t)(kt_) * 64 + vS0),             \
        (__attribute__((address_space(3))) void*)&Vl[buf_][ldsOff0], 16, 0, 0);                     \
    __builtin_amdgcn_global_load_lds(                                                               \
        (const __attribute__((address_space(1))) void*)(vB + (size_t)(kt_) * 64 + vS1),             \
        (__attribute__((address_space(3))) void*)&Vl[buf_][ldsOff1], 16, 0, 0);                     \
  } while (0)

  float m0[4], s0[4];
#pragma unroll
  for (int r = 0; r < 4; ++r) { m0[r] = -NEG_MAX; s0[r] = 0.f; }

  // ---------------- Phase 1: row stats (per-lane online, merge once) ----------------
  STAGE_K(0, 0);
  __syncthreads();
  int cur = 0;
  for (int kt = 0; kt < 32; ++kt) {
    if (kt + 1 < 32) STAGE_K(kt + 1, cur ^ 1);
    f32x4 acc[4];
#pragma unroll
    for (int n = 0; n < 4; ++n) {
      const int rb = (n * 16 + lr) * 64;
      bf16x8 kb0 = *reinterpret_cast<const bf16x8*>(&Kl[cur][rb + sA]);
      bf16x8 kb1 = *reinterpret_cast<const bf16x8*>(&Kl[cur][rb + sBo]);
      acc[n] = (f32x4){0.f, 0.f, 0.f, 0.f};
      acc[n] = __builtin_amdgcn_mfma_f32_16x16x32_bf16(qf0, kb0, acc[n], 0, 0, 0);
      acc[n] = __builtin_amdgcn_mfma_f32_16x16x32_bf16(qf1, kb1, acc[n], 0, 0, 0);
    }
    const int fl = flags[fbase + kt];
    if (fl) {
#pragma unroll
      for (int r = 0; r < 4; ++r) {
        float xv[4];
#pragma unroll
        for (int n = 0; n < 4; ++n) xv[n] = acc[n][r] * 0.125f;
        const float tm = fmaxf(fmaxf(xv[0], xv[1]), fmaxf(xv[2], xv[3]));
        const float nm = fmaxf(m0[r], tm);
        const float ps = __expf(xv[0] - nm) + __expf(xv[1] - nm) + __expf(xv[2] - nm) + __expf(xv[3] - nm);
        s0[r] = s0[r] * __expf(m0[r] - nm) + ps;
        m0[r] = nm;
      }
    } else {
#pragma unroll
      for (int r = 0; r < 4; ++r) {
        const int qrow = q0 + w * 16 + lg * 4 + r;
        const float* mp = mbase + (size_t)qrow * 2048 + kt * 64;
        float xv[4];
#pragma unroll
        for (int n = 0; n < 4; ++n) {
          const float mv = mp[n * 16 + lr];
          xv[n] = acc[n][r] * 0.125f + (1.0f - mv) * (-NEG_MAX);
        }
        const float tm = fmaxf(fmaxf(xv[0], xv[1]), fmaxf(xv[2], xv[3]));
        const float nm = fmaxf(m0[r], tm);
        const float ps = __expf(xv[0] - nm) + __expf(xv[1] - nm) + __expf(xv[2] - nm) + __expf(xv[3] - nm);
        s0[r] = s0[r] * __expf(m0[r] - nm) + ps;
        m0[r] = nm;
      }
    }
    __syncthreads();
    cur ^= 1;
  }

  // merge (m,s) across the 16 lanes sharing each row
  float inv_s[4];
#pragma unroll
  for (int r = 0; r < 4; ++r) {
#pragma unroll
    for (int dd = 1; dd < 16; dd <<= 1) {
      const float om = __shfl_xor(m0[r], dd);
      const float os = __shfl_xor(s0[r], dd);
      const float nm = fmaxf(m0[r], om);
      s0[r] = s0[r] * __expf(m0[r] - nm) + os * __expf(om - nm);
      m0[r] = nm;
    }
    inv_s[r] = 1.0f / s0[r];
  }

  f32x4 cacc[4];
#pragma unroll
  for (int n = 0; n < 4; ++n) cacc[n] = (f32x4){0.f, 0.f, 0.f, 0.f};

  // ---------------- Phase 2: weights + PV ----------------
  STAGE_K(0, 0);
  STAGE_V(0, 0);
  __syncthreads();
  cur = 0;
  for (int kt = 0; kt < 32; ++kt) {
    if (kt + 1 < 32) { STAGE_K(kt + 1, cur ^ 1); STAGE_V(kt + 1, cur ^ 1); }
    f32x4 acc[4];
#pragma unroll
    for (int n = 0; n < 4; ++n) {
      const int rb = (n * 16 + lr) * 64;
      bf16x8 kb0 = *reinterpret_cast<const bf16x8*>(&Kl[cur][rb + sA]);
      bf16x8 kb1 = *reinterpret_cast<const bf16x8*>(&Kl[cur][rb + sBo]);
      acc[n] = (f32x4){0.f, 0.f, 0.f, 0.f};
      acc[n] = __builtin_amdgcn_mfma_f32_16x16x32_bf16(qf0, kb0, acc[n], 0, 0, 0);
      acc[n] = __builtin_amdgcn_mfma_f32_16x16x32_bf16(qf1, kb1, acc[n], 0, 0, 0);
    }
    const int fl = flags[fbase + kt];
#pragma unroll
    for (int r = 0; r < 4; ++r) {
      const int qrow = q0 + w * 16 + lg * 4 + r;
      float* wp = wout + ((size_t)bh * 2048 + qrow) * 2048 + kt * 64;
      const int row2 = w * 16 + lg * 4 + r;
      const int rx = ((lg * 4 + r) & 7) << 3;
      if (fl) {
#pragma unroll
        for (int n = 0; n < 4; ++n) {
          const float x = acc[n][r] * 0.125f;
          const float wgt = __expf(x - m0[r]) * inv_s[r];
          wp[n * 16 + lr] = wgt;
          Wl[row2 * 64 + ((n * 16 + lr) ^ rx)] = f2bf(wgt);
        }
      } else {
        const float* mp = mbase + (size_t)qrow * 2048 + kt * 64;
#pragma unroll
        for (int n = 0; n < 4; ++n) {
          const float mv = mp[n * 16 + lr];
          const float x = acc[n][r] * 0.125f + (1.0f - mv) * (-NEG_MAX);
          const float wgt = __expf(x - m0[r]) * inv_s[r];
          wp[n * 16 + lr] = wgt;
          Wl[row2 * 64 + ((n * 16 + lr) ^ rx)] = f2bf(wgt);
        }
      }
    }
    __syncthreads();
    const int rowA = (w * 16 + lr) * 64;
    const bf16x8 a0 = *reinterpret_cast<const bf16x8*>(&Wl[rowA + sA]);
    const bf16x8 a1 = *reinterpret_cast<const bf16x8*>(&Wl[rowA + sBo]);
#pragma unroll
    for (int n = 0; n < 4; ++n) {
      const int rb = (n * 16 + lr) * 64;
      bf16x8 vb0 = *reinterpret_cast<const bf16x8*>(&Vl[cur][rb + sA]);
      bf16x8 vb1 = *reinterpret_cast<const bf16x8*>(&Vl[cur][rb + sBo]);
      cacc[n] = __builtin_amdgcn_mfma_f32_16x16x32_bf16(a0, vb0, cacc[n], 0, 0, 0);
      cacc[n] = __builtin_amdgcn_mfma_f32_16x16x32_bf16(a1, vb1, cacc[n], 0, 0, 0);
    }
    __syncthreads();
    cur ^= 1;
  }

#pragma unroll
  for (int n = 0; n < 4; ++n) {
#pragma unroll
    for (int r = 0; r < 4; ++r) {
      const int ss = q0 + w * 16 + lg * 4 + r;
      const int col = h * 64 + n * 16 + lr;
      ctx[((size_t)b * 2048 + ss) * 1024 + col] = f2bf(cacc[n][r]);
    }
  }
#undef STAGE_K
#undef STAGE_V
}

extern "C" void kernel_launch(void* const* d_in, const int* in_sizes, int n_in,
                              void* d_out, int out_size, void* d_ws, size_t ws_size,
                              hipStream_t stream) {
  const float* query = (const float*)d_in[0];
  const float* key   = (const float*)d_in[1];
  const float* value = (const float*)d_in[2];
  const float* mask  = (const float*)d_in[3];
  const float* wq = (const float*)d_in[4];
  const float* bq = (const float*)d_in[5];
  const float* wk = (const float*)d_in[6];
  const float* bk = (const float*)d_in[7];
  const float* wv = (const float*)d_in[8];
  const float* bv = (const float*)d_in[9];
  const float* wo = (const float*)d_in[10];
  const float* bo = (const float*)d_in[11];

  unsigned short* Qbf = (unsigned short*)d_ws;      // [B,H,S,64] bf16
  unsigned short* Kbf = Qbf + 4194304;              // [B,H,S,64] bf16
  unsigned short* Vtb = Kbf + 4194304;              // [B,H,64,S] bf16
  unsigned short* ctx = Vtb + 4194304;              // [B,S,1024] bf16
  unsigned short* xbf = ctx + 4194304;              // input staging
  unsigned short* wbf = xbf + 4194304;              // weight staging
  int* flags = (int*)(wbf + 1048576);               // [B,32,32] tile flags

  float* outp = (float*)d_out;            // [B,S,1024] fp32
  float* wout = outp + 4194304;           // [B,H,S,S] fp32

  dim3 gg(8, 32);

  mask_scan<<<2048, 256, 0, stream>>>(mask, flags);

  cvt_f32_bf16<<<4096, 256, 0, stream>>>(query, xbf, 1048576);
  cvt_f32_bf16<<<1024, 256, 0, stream>>>(wq, wbf, 262144);
  gemm_bt<0><<<gg, 256, 0, stream>>>(xbf, wbf, bq, nullptr, Qbf);

  cvt_f32_bf16<<<4096, 256, 0, stream>>>(key, xbf, 1048576);
  cvt_f32_bf16<<<1024, 256, 0, stream>>>(wk, wbf, 262144);
  gemm_bt<0><<<gg, 256, 0, stream>>>(xbf, wbf, bk, nullptr, Kbf);

  cvt_f32_bf16<<<4096, 256, 0, stream>>>(value, xbf, 1048576);
  cvt_f32_bf16<<<1024, 256, 0, stream>>>(wv, wbf, 262144);
  gemm_bt<1><<<gg, 256, 0, stream>>>(xbf, wbf, bv, nullptr, Vtb);

  attn_fused<<<1024, 256, 0, stream>>>(Qbf, Kbf, Vtb, mask, flags, wout, ctx);

  cvt_f32_bf16<<<1024, 256, 0, stream>>>(wo, wbf, 262144);
  gemm_bt<2><<<gg, 256, 0, stream>>>(ctx, wbf, bo, outp, nullptr);
}

// Round 5
// 354.915 us; speedup vs baseline: 1.5377x; 1.0764x over previous
//
#include <hip/hip_runtime.h>
#include <cstdint>

typedef short bf16x8 __attribute__((ext_vector_type(8)));
typedef float f32x4 __attribute__((ext_vector_type(4)));

#define NEG_MAX 3.402823466e38f

__device__ __forceinline__ unsigned short f2bf(float f) {
  uint32_t u = __builtin_bit_cast(uint32_t, f);
  u += 0x7FFFu + ((u >> 16) & 1u);
  return (unsigned short)(u >> 16);
}

__device__ __forceinline__ bf16x8 pack8(float4 x, float4 y) {
  bf16x8 r;
  r[0] = (short)f2bf(x.x); r[1] = (short)f2bf(x.y); r[2] = (short)f2bf(x.z); r[3] = (short)f2bf(x.w);
  r[4] = (short)f2bf(y.x); r[5] = (short)f2bf(y.y); r[6] = (short)f2bf(y.z); r[7] = (short)f2bf(y.w);
  return r;
}

// Convert the 4 weight matrices (each [1024][1024] fp32) to bf16, contiguous.
__global__ __launch_bounds__(256) void cvt_w(const float* __restrict__ wq, const float* __restrict__ wk,
                                             const float* __restrict__ wv, const float* __restrict__ wo,
                                             unsigned short* __restrict__ out) {
  int i = blockIdx.x * 256 + threadIdx.x;            // 0 .. 4*262144-1 (float4 units)
  const int sel = i >> 18;                           // 262144 float4 per matrix
  const int idx = i & 0x3FFFF;
  const float* src = (sel == 0) ? wq : (sel == 1) ? wk : (sel == 2) ? wv : wo;
  float4 v = reinterpret_cast<const float4*>(src)[idx];
  ushort4 o;
  o.x = f2bf(v.x); o.y = f2bf(v.y); o.z = f2bf(v.z); o.w = f2bf(v.w);
  reinterpret_cast<ushort4*>(out)[i] = o;
}

// Per (b, q64-tile, k64-tile): flag = 1 if mask tile is entirely 1.0f, else 0.
__global__ __launch_bounds__(256) void mask_scan(const float* __restrict__ mask,
                                                 int* __restrict__ flags) {
  const int blk = blockIdx.x;
  const int kt = blk & 31, qt = (blk >> 5) & 31, b = blk >> 10;
  const float* base = mask + ((size_t)b * 2048 + qt * 64) * 2048 + kt * 64;
  const int t = threadIdx.x;
  const int row = t >> 2, c0 = (t & 3) * 16;
  const float4* p = reinterpret_cast<const float4*>(base + (size_t)row * 2048 + c0);
  bool ones = true;
#pragma unroll
  for (int i = 0; i < 4; ++i) {
    float4 v = p[i];
    ones = ones && (v.x == 1.f) && (v.y == 1.f) && (v.z == 1.f) && (v.w == 1.f);
  }
  unsigned long long ball = __ballot(ones);
  __shared__ int sf[4];
  if ((t & 63) == 0) sf[t >> 6] = (ball == ~0ull) ? 1 : 0;
  __syncthreads();
  if (t == 0) flags[blk] = sf[0] & sf[1] & sf[2] & sf[3];
}

// Fused Q/K/V projection: z = blockIdx.z selects {query,key,value}.
// A fp32 [4096][1024] reg-staged->bf16 LDS; W bf16 via global_load_lds.
// z<2: bf16 head-split [B,H,S,64]; z==2: bf16 [B,H,64,S] (transposed V).
__global__ __launch_bounds__(256) void gemm_qkv(const float* __restrict__ Aq,
                                                const float* __restrict__ Ak,
                                                const float* __restrict__ Av,
                                                const unsigned short* __restrict__ W3,
                                                const float* __restrict__ bq,
                                                const float* __restrict__ bk,
                                                const float* __restrict__ bv,
                                                unsigned short* __restrict__ Qbf,
                                                unsigned short* __restrict__ Kbf,
                                                unsigned short* __restrict__ Vtb) {
  constexpr int KD = 1024;
  __shared__ __align__(16) unsigned short Al[128 * 32];
  __shared__ __align__(16) unsigned short Bl[128 * 32];
  const int tid = threadIdx.x;
  const int l = tid & 63;
  const int w = tid >> 6;
  const int lr = l & 15;
  const int lg = l >> 4;
  const int gm = blockIdx.y;
  const int gn = blockIdx.x;
  const int z = blockIdx.z;
  const int wr = w >> 1;
  const int wc = w & 1;

  const float* Af = (z == 0) ? Aq : (z == 1) ? Ak : Av;
  const float* bias = (z == 0) ? bq : (z == 1) ? bk : bv;
  const unsigned short* Bw = W3 + (size_t)z * 1048576;
  unsigned short* Cb = (z == 0) ? Qbf : (z == 1) ? Kbf : Vtb;

  f32x4 acc[4][4];
#pragma unroll
  for (int m = 0; m < 4; ++m)
#pragma unroll
    for (int n = 0; n < 4; ++n) acc[m][n] = (f32x4){0.f, 0.f, 0.f, 0.f};

  // B staging (gload_lds): wave chunks as before
  const int c0 = w * 2;
  const int srow = (l >> 2);
  const int scol = (l & 3) * 8;
  const unsigned short* gB = Bw + (size_t)(gn * 128) * KD;

  // A staging (fp32 reg): thread covers row=tid>>1, 16 cols at half*16
  const int arow = tid >> 1;
  const int ahalf = tid & 1;
  const float* gA = Af + (size_t)(gm * 128 + arow) * KD + ahalf * 16;

  float4 ap[4];
  {
    const float4* p = reinterpret_cast<const float4*>(gA);
#pragma unroll
    for (int i = 0; i < 4; ++i) ap[i] = p[i];
  }

  for (int kt = 0; kt < 32; ++kt) {
    const int k0 = kt * 32;
    const unsigned short* b0 = gB + (size_t)(c0 * 16 + srow) * KD + k0 + scol;
    const unsigned short* b1 = b0 + (size_t)16 * KD;
    __builtin_amdgcn_global_load_lds((const __attribute__((address_space(1))) void*)b0,
                                     (__attribute__((address_space(3))) void*)&Bl[c0 * 512], 16, 0, 0);
    __builtin_amdgcn_global_load_lds((const __attribute__((address_space(1))) void*)b1,
                                     (__attribute__((address_space(3))) void*)&Bl[c0 * 512 + 512], 16, 0, 0);
    // convert previously-loaded A regs into LDS
    {
      bf16x8* dst = reinterpret_cast<bf16x8*>(&Al[arow * 32 + ahalf * 16]);
      dst[0] = pack8(ap[0], ap[1]);
      dst[1] = pack8(ap[2], ap[3]);
    }
    __syncthreads();
    // prefetch next A tile while MFMAs run
    if (kt + 1 < 32) {
      const float4* p = reinterpret_cast<const float4*>(gA + (kt + 1) * 32);
#pragma unroll
      for (int i = 0; i < 4; ++i) ap[i] = p[i];
    }
    bf16x8 af[4], bfr[4];
#pragma unroll
    for (int m = 0; m < 4; ++m)
      af[m] = *reinterpret_cast<const bf16x8*>(&Al[(wr * 64 + m * 16 + lr) * 32 + lg * 8]);
#pragma unroll
    for (int n = 0; n < 4; ++n)
      bfr[n] = *reinterpret_cast<const bf16x8*>(&Bl[(wc * 64 + n * 16 + lr) * 32 + lg * 8]);
#pragma unroll
    for (int m = 0; m < 4; ++m)
#pragma unroll
      for (int n = 0; n < 4; ++n)
        acc[m][n] = __builtin_amdgcn_mfma_f32_16x16x32_bf16(af[m], bfr[n], acc[m][n], 0, 0, 0);
    __syncthreads();
  }

#pragma unroll
  for (int m = 0; m < 4; ++m) {
#pragma unroll
    for (int n = 0; n < 4; ++n) {
      const int colg = gn * 128 + wc * 64 + n * 16 + lr;
      const float bv2 = bias[colg];
#pragma unroll
      for (int r = 0; r < 4; ++r) {
        const int rowg = gm * 128 + wr * 64 + m * 16 + lg * 4 + r;
        const float v = acc[m][n][r] + bv2;
        const int bb = rowg >> 11, ss = rowg & 2047;
        const int hh = colg >> 6, dk = colg & 63;
        if (z < 2)
          Cb[(((size_t)bb * 16 + hh) * 2048 + ss) * 64 + dk] = f2bf(v);
        else
          Cb[(((size_t)bb * 16 + hh) * 64 + dk) * 2048 + ss] = f2bf(v);
      }
    }
  }
}

// Output projection: C = ctx @ wo^T + bo, fp32 out. A bf16 via gload_lds.
__global__ __launch_bounds__(256) void gemm_out(const unsigned short* __restrict__ A,
                                                const unsigned short* __restrict__ Bw,
                                                const float* __restrict__ bias,
                                                float* __restrict__ Cf) {
  constexpr int KD = 1024;
  __shared__ __align__(16) unsigned short Al[128 * 32];
  __shared__ __align__(16) unsigned short Bl[128 * 32];
  const int tid = threadIdx.x;
  const int l = tid & 63;
  const int w = tid >> 6;
  const int lr = l & 15;
  const int lg = l >> 4;
  const int gm = blockIdx.y;
  const int gn = blockIdx.x;
  const int wr = w >> 1;
  const int wc = w & 1;

  f32x4 acc[4][4];
#pragma unroll
  for (int m = 0; m < 4; ++m)
#pragma unroll
    for (int n = 0; n < 4; ++n) acc[m][n] = (f32x4){0.f, 0.f, 0.f, 0.f};

  const int c0 = w * 2;
  const int srow = (l >> 2);
  const int scol = (l & 3) * 8;
  const unsigned short* gA = A + (size_t)(gm * 128) * KD;
  const unsigned short* gB = Bw + (size_t)(gn * 128) * KD;

  for (int kt = 0; kt < 32; ++kt) {
    const int k0 = kt * 32;
    const unsigned short* a0 = gA + (size_t)(c0 * 16 + srow) * KD + k0 + scol;
    const unsigned short* a1 = a0 + (size_t)16 * KD;
    const unsigned short* b0 = gB + (size_t)(c0 * 16 + srow) * KD + k0 + scol;
    const unsigned short* b1 = b0 + (size_t)16 * KD;
    __builtin_amdgcn_global_load_lds((const __attribute__((address_space(1))) void*)a0,
                                     (__attribute__((address_space(3))) void*)&Al[c0 * 512], 16, 0, 0);
    __builtin_amdgcn_global_load_lds((const __attribute__((address_space(1))) void*)a1,
                                     (__attribute__((address_space(3))) void*)&Al[c0 * 512 + 512], 16, 0, 0);
    __builtin_amdgcn_global_load_lds((const __attribute__((address_space(1))) void*)b0,
                                     (__attribute__((address_space(3))) void*)&Bl[c0 * 512], 16, 0, 0);
    __builtin_amdgcn_global_load_lds((const __attribute__((address_space(1))) void*)b1,
                                     (__attribute__((address_space(3))) void*)&Bl[c0 * 512 + 512], 16, 0, 0);
    __syncthreads();
    bf16x8 af[4], bfr[4];
#pragma unroll
    for (int m = 0; m < 4; ++m)
      af[m] = *reinterpret_cast<const bf16x8*>(&Al[(wr * 64 + m * 16 + lr) * 32 + lg * 8]);
#pragma unroll
    for (int n = 0; n < 4; ++n)
      bfr[n] = *reinterpret_cast<const bf16x8*>(&Bl[(wc * 64 + n * 16 + lr) * 32 + lg * 8]);
#pragma unroll
    for (int m = 0; m < 4; ++m)
#pragma unroll
      for (int n = 0; n < 4; ++n)
        acc[m][n] = __builtin_amdgcn_mfma_f32_16x16x32_bf16(af[m], bfr[n], acc[m][n], 0, 0, 0);
    __syncthreads();
  }

#pragma unroll
  for (int m = 0; m < 4; ++m) {
#pragma unroll
    for (int n = 0; n < 4; ++n) {
      const int colg = gn * 128 + wc * 64 + n * 16 + lr;
      const float bv = bias[colg];
#pragma unroll
      for (int r = 0; r < 4; ++r) {
        const int rowg = gm * 128 + wr * 64 + m * 16 + lg * 4 + r;
        Cf[(size_t)rowg * 1024 + colg] = acc[m][n][r] + bv;
      }
    }
  }
}

// One block = (b,h, 64 q-rows), 4 waves x 16 rows. XCD-swizzled blockIdx.
// Phase 1: counted-vmcnt pipeline (raw s_barrier, loads stay in flight).
// Phase 2: recompute + weights write + PV (classic __syncthreads dbuf).
__global__ __launch_bounds__(256) void attn_fused(const unsigned short* __restrict__ Q,
                                                  const unsigned short* __restrict__ Kb,
                                                  const unsigned short* __restrict__ Vt,
                                                  const float* __restrict__ mask,
                                                  const int* __restrict__ flags,
                                                  float* __restrict__ wout,
                                                  unsigned short* __restrict__ ctx) {
  const int tid = threadIdx.x;
  const int l = tid & 63;
  const int w = tid >> 6;
  const int lr = l & 15;
  const int lg = l >> 4;

  const int d = blockIdx.x;
  const int bh = (d >> 8) * 8 + (d & 7);
  const int qt = (d >> 3) & 31;
  const int b = bh >> 4, h = bh & 15;
  const int q0 = qt * 64;

  __shared__ __align__(16) unsigned short Kl[2][4096];
  __shared__ __align__(16) unsigned short Vl[2][4096];
  __shared__ __align__(16) unsigned short Wl[4096];

  const size_t qoff = ((size_t)bh * 2048 + (q0 + w * 16 + lr)) * 64 + lg * 8;
  const bf16x8 qf0 = *reinterpret_cast<const bf16x8*>(Q + qoff);
  const bf16x8 qf1 = *reinterpret_cast<const bf16x8*>(Q + qoff + 32);

  const int seg0 = w * 128 + l;
  const int seg1 = seg0 + 64;
  const int r0s = seg0 >> 3, c0x = (seg0 & 7) ^ (r0s & 7);
  const int r1s = seg1 >> 3, c1x = (seg1 & 7) ^ (r1s & 7);
  const unsigned short* kB = Kb + (size_t)bh * 131072;
  const unsigned short* vB = Vt + (size_t)bh * 131072;
  const size_t kS0 = (size_t)r0s * 64 + c0x * 8;
  const size_t kS1 = (size_t)r1s * 64 + c1x * 8;
  const size_t vS0 = (size_t)r0s * 2048 + c0x * 8;
  const size_t vS1 = (size_t)r1s * 2048 + c1x * 8;
  const int ldsOff0 = w * 1024;
  const int ldsOff1 = w * 1024 + 512;

  const int sA = (lg ^ (lr & 7)) << 3;
  const int sBo = ((4 + lg) ^ (lr & 7)) << 3;

  const int fbase = (b * 32 + qt) * 32;
  const float* mbase = mask + (size_t)b * 2048 * 2048;

#define STAGE_K(kt_, buf_)                                                                          \
  do {                                                                                              \
    __builtin_amdgcn_global_load_lds(                                                               \
        (const __attribute__((address_space(1))) void*)(kB + (size_t)(kt_) * 4096 + kS0),           \
        (__attribute__((address_space(3))) void*)&Kl[buf_][ldsOff0], 16, 0, 0);                     \
    __builtin_amdgcn_global_load_lds(                                                               \
        (const __attribute__((address_space(1))) void*)(kB + (size_t)(kt_) * 4096 + kS1),           \
        (__attribute__((address_space(3))) void*)&Kl[buf_][ldsOff1], 16, 0, 0);                     \
  } while (0)
#define STAGE_V(kt_, buf_)                                                                          \
  do {                                                                                              \
    __builtin_amdgcn_global_load_lds(                                                               \
        (const __attribute__((address_space(1))) void*)(vB + (size_t)(kt_) * 64 + vS0),             \
        (__attribute__((address_space(3))) void*)&Vl[buf_][ldsOff0], 16, 0, 0);                     \
    __builtin_amdgcn_global_load_lds(                                                               \
        (const __attribute__((address_space(1))) void*)(vB + (size_t)(kt_) * 64 + vS1),             \
        (__attribute__((address_space(3))) void*)&Vl[buf_][ldsOff1], 16, 0, 0);                     \
  } while (0)

  float m0[4], s0[4];
#pragma unroll
  for (int r = 0; r < 4; ++r) { m0[r] = -NEG_MAX; s0[r] = 0.f; }

  // ---------------- Phase 1: counted-vmcnt pipelined stats pass ----------------
  STAGE_K(0, 0);
  STAGE_K(1, 1);
  int cur = 0;
  for (int kt = 0; kt < 32; ++kt) {
    if (kt < 31) {
      asm volatile("s_waitcnt vmcnt(2)" ::: "memory");
    } else {
      asm volatile("s_waitcnt vmcnt(0)" ::: "memory");
    }
    __builtin_amdgcn_s_barrier();
    __builtin_amdgcn_sched_barrier(0);
    f32x4 acc[4];
#pragma unroll
    for (int n = 0; n < 4; ++n) {
      const int rb = (n * 16 + lr) * 64;
      bf16x8 kb0 = *reinterpret_cast<const bf16x8*>(&Kl[cur][rb + sA]);
      bf16x8 kb1 = *reinterpret_cast<const bf16x8*>(&Kl[cur][rb + sBo]);
      acc[n] = (f32x4){0.f, 0.f, 0.f, 0.f};
      acc[n] = __builtin_amdgcn_mfma_f32_16x16x32_bf16(qf0, kb0, acc[n], 0, 0, 0);
      acc[n] = __builtin_amdgcn_mfma_f32_16x16x32_bf16(qf1, kb1, acc[n], 0, 0, 0);
    }
    const int fl = flags[fbase + kt];
    if (fl) {
#pragma unroll
      for (int r = 0; r < 4; ++r) {
        float xv[4];
#pragma unroll
        for (int n = 0; n < 4; ++n) xv[n] = acc[n][r] * 0.125f;
        const float tm = fmaxf(fmaxf(xv[0], xv[1]), fmaxf(xv[2], xv[3]));
        const float nm = fmaxf(m0[r], tm);
        const float ps = __expf(xv[0] - nm) + __expf(xv[1] - nm) + __expf(xv[2] - nm) + __expf(xv[3] - nm);
        s0[r] = s0[r] * __expf(m0[r] - nm) + ps;
        m0[r] = nm;
      }
    } else {
#pragma unroll
      for (int r = 0; r < 4; ++r) {
        const int qrow = q0 + w * 16 + lg * 4 + r;
        const float* mp = mbase + (size_t)qrow * 2048 + kt * 64;
        float xv[4];
#pragma unroll
        for (int n = 0; n < 4; ++n) {
          const float mv = mp[n * 16 + lr];
          xv[n] = acc[n][r] * 0.125f + (1.0f - mv) * (-NEG_MAX);
        }
        const float tm = fmaxf(fmaxf(xv[0], xv[1]), fmaxf(xv[2], xv[3]));
        const float nm = fmaxf(m0[r], tm);
        const float ps = __expf(xv[0] - nm) + __expf(xv[1] - nm) + __expf(xv[2] - nm) + __expf(xv[3] - nm);
        s0[r] = s0[r] * __expf(m0[r] - nm) + ps;
        m0[r] = nm;
      }
    }
    __builtin_amdgcn_sched_barrier(0);
    __builtin_amdgcn_s_barrier();
    if (kt + 2 < 32) STAGE_K(kt + 2, cur);
    cur ^= 1;
  }

  // merge (m,s) across the 16 lanes sharing each row
  float inv_s[4];
#pragma unroll
  for (int r = 0; r < 4; ++r) {
#pragma unroll
    for (int dd = 1; dd < 16; dd <<= 1) {
      const float om = __shfl_xor(m0[r], dd);
      const float os = __shfl_xor(s0[r], dd);
      const float nm = fmaxf(m0[r], om);
      s0[r] = s0[r] * __expf(m0[r] - nm) + os * __expf(om - nm);
      m0[r] = nm;
    }
    inv_s[r] = 1.0f / s0[r];
  }

  f32x4 cacc[4];
#pragma unroll
  for (int n = 0; n < 4; ++n) cacc[n] = (f32x4){0.f, 0.f, 0.f, 0.f};

  // ---------------- Phase 2: weights + PV ----------------
  STAGE_K(0, 0);
  STAGE_V(0, 0);
  __syncthreads();
  cur = 0;
  for (int kt = 0; kt < 32; ++kt) {
    if (kt + 1 < 32) { STAGE_K(kt + 1, cur ^ 1); STAGE_V(kt + 1, cur ^ 1); }
    f32x4 acc[4];
#pragma unroll
    for (int n = 0; n < 4; ++n) {
      const int rb = (n * 16 + lr) * 64;
      bf16x8 kb0 = *reinterpret_cast<const bf16x8*>(&Kl[cur][rb + sA]);
      bf16x8 kb1 = *reinterpret_cast<const bf16x8*>(&Kl[cur][rb + sBo]);
      acc[n] = (f32x4){0.f, 0.f, 0.f, 0.f};
      acc[n] = __builtin_amdgcn_mfma_f32_16x16x32_bf16(qf0, kb0, acc[n], 0, 0, 0);
      acc[n] = __builtin_amdgcn_mfma_f32_16x16x32_bf16(qf1, kb1, acc[n], 0, 0, 0);
    }
    const int fl = flags[fbase + kt];
#pragma unroll
    for (int r = 0; r < 4; ++r) {
      const int qrow = q0 + w * 16 + lg * 4 + r;
      float* wp = wout + ((size_t)bh * 2048 + qrow) * 2048 + kt * 64;
      const int row2 = w * 16 + lg * 4 + r;
      const int rx = ((lg * 4 + r) & 7) << 3;
      if (fl) {
#pragma unroll
        for (int n = 0; n < 4; ++n) {
          const float x = acc[n][r] * 0.125f;
          const float wgt = __expf(x - m0[r]) * inv_s[r];
          wp[n * 16 + lr] = wgt;
          Wl[row2 * 64 + ((n * 16 + lr) ^ rx)] = f2bf(wgt);
        }
      } else {
        const float* mp = mbase + (size_t)qrow * 2048 + kt * 64;
#pragma unroll
        for (int n = 0; n < 4; ++n) {
          const float mv = mp[n * 16 + lr];
          const float x = acc[n][r] * 0.125f + (1.0f - mv) * (-NEG_MAX);
          const float wgt = __expf(x - m0[r]) * inv_s[r];
          wp[n * 16 + lr] = wgt;
          Wl[row2 * 64 + ((n * 16 + lr) ^ rx)] = f2bf(wgt);
        }
      }
    }
    __syncthreads();
    const int rowA = (w * 16 + lr) * 64;
    const bf16x8 a0 = *reinterpret_cast<const bf16x8*>(&Wl[rowA + sA]);
    const bf16x8 a1 = *reinterpret_cast<const bf16x8*>(&Wl[rowA + sBo]);
#pragma unroll
    for (int n = 0; n < 4; ++n) {
      const int rb = (n * 16 + lr) * 64;
      bf16x8 vb0 = *reinterpret_cast<const bf16x8*>(&Vl[cur][rb + sA]);
      bf16x8 vb1 = *reinterpret_cast<const bf16x8*>(&Vl[cur][rb + sBo]);
      cacc[n] = __builtin_amdgcn_mfma_f32_16x16x32_bf16(a0, vb0, cacc[n], 0, 0, 0);
      cacc[n] = __builtin_amdgcn_mfma_f32_16x16x32_bf16(a1, vb1, cacc[n], 0, 0, 0);
    }
    __syncthreads();
    cur ^= 1;
  }

#pragma unroll
  for (int n = 0; n < 4; ++n) {
#pragma unroll
    for (int r = 0; r < 4; ++r) {
      const int ss = q0 + w * 16 + lg * 4 + r;
      const int col = h * 64 + n * 16 + lr;
      ctx[((size_t)b * 2048 + ss) * 1024 + col] = f2bf(cacc[n][r]);
    }
  }
#undef STAGE_K
#undef STAGE_V
}

extern "C" void kernel_launch(void* const* d_in, const int* in_sizes, int n_in,
                              void* d_out, int out_size, void* d_ws, size_t ws_size,
                              hipStream_t stream) {
  const float* query = (const float*)d_in[0];
  const float* key   = (const float*)d_in[1];
  const float* value = (const float*)d_in[2];
  const float* mask  = (const float*)d_in[3];
  const float* wq = (const float*)d_in[4];
  const float* bq = (const float*)d_in[5];
  const float* wk = (const float*)d_in[6];
  const float* bk = (const float*)d_in[7];
  const float* wv = (const float*)d_in[8];
  const float* bv = (const float*)d_in[9];
  const float* wo = (const float*)d_in[10];
  const float* bo = (const float*)d_in[11];

  unsigned short* Qbf = (unsigned short*)d_ws;      // [B,H,S,64] bf16   8 MB
  unsigned short* Kbf = Qbf + 4194304;              // [B,H,S,64] bf16   8 MB
  unsigned short* Vtb = Kbf + 4194304;              // [B,H,64,S] bf16   8 MB
  unsigned short* ctx = Vtb + 4194304;              // [B,S,1024] bf16   8 MB
  unsigned short* wbf4 = ctx + 4194304;             // wq|wk|wv|wo bf16  8 MB
  int* flags = (int*)(wbf4 + 4194304);              // [B,32,32] flags   8 KB

  float* outp = (float*)d_out;            // [B,S,1024] fp32
  float* wout = outp + 4194304;           // [B,H,S,S] fp32

  mask_scan<<<2048, 256, 0, stream>>>(mask, flags);
  cvt_w<<<4096, 256, 0, stream>>>(wq, wk, wv, wo, wbf4);

  dim3 gq(8, 32, 3);
  gemm_qkv<<<gq, 256, 0, stream>>>(query, key, value, wbf4, bq, bk, bv, Qbf, Kbf, Vtb);

  attn_fused<<<1024, 256, 0, stream>>>(Qbf, Kbf, Vtb, mask, flags, wout, ctx);

  dim3 gg(8, 32);
  gemm_out<<<gg, 256, 0, stream>>>(ctx, wbf4 + 3145728, bo, outp);
}